// Round 3
// baseline (75.887 us; speedup 1.0000x reference)
//
#include <hip/hip_runtime.h>

typedef __attribute__((ext_vector_type(8))) short short8;
typedef __attribute__((ext_vector_type(4))) short short4v;
typedef __attribute__((ext_vector_type(4))) float f32x4;

#define MFMA_16x16x32_BF16(A, B, C) __builtin_amdgcn_mfma_f32_16x16x32_bf16(A, B, C, 0, 0, 0)

// float -> bf16 bits, round-to-nearest-even (inputs always finite here)
__device__ __forceinline__ unsigned short f2bf(float x) {
    unsigned int u = __builtin_bit_cast(unsigned int, x);
    u = (u + 0x7FFFu + ((u >> 16) & 1u)) >> 16;
    return (unsigned short)u;
}

// ---------------------------------------------------------------------------
// Kernel 1: pack Wk|Wq|Wv (fp32 [1024][64]) -> Wt bf16 [192][1024] (transposed)
// ---------------------------------------------------------------------------
__global__ __launch_bounds__(256) void wconv_kernel(const float* __restrict__ Wk,
                                                    const float* __restrict__ Wq,
                                                    const float* __restrict__ Wv,
                                                    unsigned short* __restrict__ Wt) {
    const int n = blockIdx.x;                       // 0..191
    const float* W = (n < 64) ? Wk : (n < 128) ? Wq : Wv;
    const int col = n & 63;
    for (int k = threadIdx.x; k < 1024; k += 256)
        Wt[(size_t)n * 1024 + k] = f2bf(W[(size_t)k * 64 + col]);
}

// ---------------------------------------------------------------------------
// Kernel 2: QKV projection, streaming no-LDS no-barrier GEMM.
// Grid 1024 x 64 thr (single wave).  Block (rt, ch): rows 32*rt..32*rt+31,
// cols 96*ch..96*ch+95 of the [16384][192] output.  A-frags direct from X
// (fp32, converted in-reg), B-frags direct from L2-resident Wt.
// In-register pipeline, in-order-vmcnt-safe issue order per step s:
//   [issue B(s+1)] [convert A(s)] [issue A(s+2)] [MFMA with B(s)]
// -> waiting on B never drains the A ring and vice versa.  Unrolled x2 so
// all ring indices are compile-time constants (no scratch).
// Outputs: Kb/Qb row-major [16384][64]; V transposed per batch Vtg[b][64][2048].
// ---------------------------------------------------------------------------
__global__ __launch_bounds__(64) void proj_kernel(const float* __restrict__ X,
                                                  const unsigned short* __restrict__ Wt,
                                                  unsigned short* __restrict__ Kb,
                                                  unsigned short* __restrict__ Qb,
                                                  unsigned short* __restrict__ Vtg) {
    const int lane = threadIdx.x;
    const int lr = lane & 15, g = lane >> 4;
    const int rt = blockIdx.x >> 1, ch = blockIdx.x & 1;
    const int r0 = rt * 32;
    const int n0 = ch * 96;

    f32x4 acc[2][6] = {};
    float4 arA[2][2][2];     // A ring [slot][tile][half] — all indices static
    short8 bfA[6], bfB[6];   // B ping-pong

    const float* xb = X + (size_t)(r0 + lr) * 1024 + 8 * g;
    const unsigned short* wb = Wt + (size_t)(n0 + lr) * 1024 + 8 * g;

#define ISSUEA(SLOT, K)                                                     \
    {                                                                       \
        _Pragma("unroll")                                                   \
        for (int ti = 0; ti < 2; ++ti) {                                    \
            const float* p = xb + ti * 16 * 1024 + (K);                     \
            arA[SLOT][ti][0] = *(const float4*)p;                           \
            arA[SLOT][ti][1] = *(const float4*)(p + 4);                     \
        }                                                                   \
    }
#define ISSUEB(DST, K)                                                     \
    {                                                                       \
        _Pragma("unroll")                                                   \
        for (int c = 0; c < 6; ++c)                                         \
            DST[c] = *(const short8*)(wb + (size_t)c * 16 * 1024 + (K));    \
    }
#define PSTEP(S, BC, BN)                                                    \
    {                                                                       \
        const int k0 = (S) * 32;                                            \
        if (k0 + 32 < 1024) ISSUEB(BN, k0 + 32);                            \
        short8 af[2];                                                       \
        _Pragma("unroll")                                                   \
        for (int ti = 0; ti < 2; ++ti) {                                    \
            _Pragma("unroll")                                               \
            for (int h = 0; h < 2; ++h) {                                   \
                float4 v = arA[(S) & 1][ti][h];                             \
                af[ti][4 * h + 0] = (short)f2bf(v.x);                       \
                af[ti][4 * h + 1] = (short)f2bf(v.y);                       \
                af[ti][4 * h + 2] = (short)f2bf(v.z);                       \
                af[ti][4 * h + 3] = (short)f2bf(v.w);                       \
            }                                                               \
        }                                                                   \
        if (k0 + 64 < 1024) ISSUEA((S) & 1, k0 + 64);                       \
        _Pragma("unroll")                                                   \
        for (int c = 0; c < 6; ++c) {                                       \
            acc[0][c] = MFMA_16x16x32_BF16(af[0], BC[c], acc[0][c]);        \
            acc[1][c] = MFMA_16x16x32_BF16(af[1], BC[c], acc[1][c]);        \
        }                                                                   \
    }

    ISSUEB(bfA, 0);
    ISSUEA(0, 0);
    ISSUEA(1, 32);

    for (int j = 0; j < 16; ++j) {
        PSTEP(2 * j, bfA, bfB);
        PSTEP(2 * j + 1, bfB, bfA);
    }
#undef PSTEP
#undef ISSUEB
#undef ISSUEA

    // ---- epilogue: C/D layout col = lane&15 (W-col), row = 4*(lane>>4)+reg ----
    const int bb = r0 >> 11;             // batch
    const int sb0 = r0 & 2047;           // s within batch
#pragma unroll
    for (int c = 0; c < 6; ++c) {
        const int cg = 6 * ch + c;       // global col-tile 0..11
#pragma unroll
        for (int ti = 0; ti < 2; ++ti) {
            const int row = r0 + 16 * ti + 4 * g;
            if (cg < 4) {
#pragma unroll
                for (int r = 0; r < 4; ++r)
                    Kb[(size_t)(row + r) * 64 + 16 * cg + lr] = f2bf(acc[ti][c][r]);
            } else if (cg < 8) {
#pragma unroll
                for (int r = 0; r < 4; ++r)
                    Qb[(size_t)(row + r) * 64 + 16 * (cg - 4) + lr] = f2bf(acc[ti][c][r]);
            } else {
                const int h = 16 * (cg - 8) + lr;
                uint2 e;
                e.x = (unsigned)f2bf(acc[ti][c][0]) | ((unsigned)f2bf(acc[ti][c][1]) << 16);
                e.y = (unsigned)f2bf(acc[ti][c][2]) | ((unsigned)f2bf(acc[ti][c][3]) << 16);
                *(uint2*)(Vtg + (size_t)bb * 64 * 2048 + (size_t)h * 2048 + sb0 + 16 * ti + 4 * g) = e;
            }
        }
    }
}

// ---------------------------------------------------------------------------
// Kernel 3: causal flash attention, band-pair blocks.
// Block = bands {63-p (hi), p (lo)} of 32 q-rows each -> exactly 65 kv-steps
// of work per block (perfect balance).  8 waves split the 65 steps
// contiguously; each wave holds private online-softmax state per 16-q tile;
// K and V^T fragments load DIRECTLY from global (L2-resident) -> no LDS, no
// barriers in the main loop.  Partials merged in LDS at the end.
// ---------------------------------------------------------------------------
__global__ __launch_bounds__(512, 2) void attn_kernel(const unsigned short* __restrict__ Kb,
                                                      const unsigned short* __restrict__ Qb,
                                                      const unsigned short* __restrict__ Vtg,
                                                      float* __restrict__ out) {
    __shared__ __attribute__((aligned(16))) float Pacc[16][32][68];  // [slot][q][h] pad 68
    __shared__ float Pml[2][16][32];                                 // m / l per slot,q

    const int t = threadIdx.x;
    const int w = t >> 6, lane = t & 63;
    const int lr = lane & 15, g = lane >> 4;
    const int p = blockIdx.x, b = blockIdx.y;
    const int nhi = 64 - p;                      // steps for hi band
    const int q0h = (63 - p) * 32, q0l = p * 32;
    const size_t rowbase = (size_t)b * 2048;
    const size_t vbase = (size_t)b * 64 * 2048;
    const float NEG_INF = -__builtin_inff();
    const float SCALE2 = 0.03125f * 1.4426950408889634f;   // d^-0.5 * log2(e)

    // Q fragments (B-operand): [sub][hh]
    short8 qfH[2][2], qfL[2][2];
#pragma unroll
    for (int sub = 0; sub < 2; ++sub)
#pragma unroll
        for (int hh = 0; hh < 2; ++hh) {
            qfH[sub][hh] = *(const short8*)(Qb + (rowbase + q0h + 16 * sub + lr) * 64 + 32 * hh + 8 * g);
            qfL[sub][hh] = *(const short8*)(Qb + (rowbase + q0l + 16 * sub + lr) * 64 + 32 * hh + 8 * g);
        }

    f32x4 accH[2][4] = {}, accL[2][4] = {};
    float mH[2] = {NEG_INF, NEG_INF}, mL[2] = {NEG_INF, NEG_INF};
    float lH[2] = {0.f, 0.f}, lL[2] = {0.f, 0.f};

    const int s0 = (w * 65) >> 3, s1 = ((w + 1) * 65) >> 3;

    auto step = [&](int kv0, int q0, const short8 (&qf)[2][2],
                    f32x4 (&acc)[2][4], float (&m2)[2], float (&ls)[2]) {
        // K A-frags direct from global: row kv0+16f+lr, cols 32hh+8g (16B)
        short8 kf[2][2];
#pragma unroll
        for (int f = 0; f < 2; ++f)
#pragma unroll
            for (int hh = 0; hh < 2; ++hh)
                kf[f][hh] = *(const short8*)(Kb + (rowbase + kv0 + 16 * f + lr) * 64 + 32 * hh + 8 * g);
        // V^T A-frags direct from Vtg: row h=16fh+lr, kv cols 4g.. / 16+4g..
        short8 vf[4];
#pragma unroll
        for (int fh = 0; fh < 4; ++fh) {
            const unsigned short* vp = Vtg + vbase + (size_t)(16 * fh + lr) * 2048 + kv0 + 4 * g;
            short4v v0 = *(const short4v*)vp;
            short4v v1 = *(const short4v*)(vp + 16);
            short8 vv;
            vv[0] = v0[0]; vv[1] = v0[1]; vv[2] = v0[2]; vv[3] = v0[3];
            vv[4] = v1[0]; vv[5] = v1[1]; vv[6] = v1[2]; vv[7] = v1[3];
            vf[fh] = vv;
        }
#pragma unroll
        for (int sub = 0; sub < 2; ++sub) {
            f32x4 sv[2];
#pragma unroll
            for (int f = 0; f < 2; ++f) {
                f32x4 x = {};
                x = MFMA_16x16x32_BF16(kf[f][0], qf[sub][0], x);
                x = MFMA_16x16x32_BF16(kf[f][1], qf[sub][1], x);
                sv[f] = x;
            }
            const int q = q0 + 16 * sub + lr;
            float pvv[8], tmax = NEG_INF;
#pragma unroll
            for (int f = 0; f < 2; ++f)
#pragma unroll
                for (int r = 0; r < 4; ++r) {
                    int kp = kv0 + 16 * f + 4 * g + r;
                    float sc = sv[f][r] * SCALE2;
                    sc = (kp <= q) ? sc : NEG_INF;
                    pvv[4 * f + r] = sc;
                    tmax = fmaxf(tmax, sc);
                }
            tmax = fmaxf(tmax, __shfl_xor(tmax, 16));
            tmax = fmaxf(tmax, __shfl_xor(tmax, 32));
            float mnew = fmaxf(m2[sub], tmax);     // finite: kv0 <= q0 <= q always
            float alpha = exp2f(m2[sub] - mnew);
            float psum = 0.f;
            short8 pf;
#pragma unroll
            for (int e = 0; e < 8; ++e) {
                float pe = exp2f(pvv[e] - mnew);
                psum += pe;
                pf[e] = (short)f2bf(pe);
            }
            psum += __shfl_xor(psum, 16);
            psum += __shfl_xor(psum, 32);
            ls[sub] = ls[sub] * alpha + psum;
            m2[sub] = mnew;
#pragma unroll
            for (int fh = 0; fh < 4; ++fh) {
                acc[sub][fh][0] *= alpha; acc[sub][fh][1] *= alpha;
                acc[sub][fh][2] *= alpha; acc[sub][fh][3] *= alpha;
                acc[sub][fh] = MFMA_16x16x32_BF16(vf[fh], pf, acc[sub][fh]);
            }
        }
    };

    const int ehi = (s1 < nhi) ? s1 : nhi;
    for (int s = s0; s < ehi; ++s) step(s * 32, q0h, qfH, accH, mH, lH);
    const int slo = (s0 > nhi) ? s0 : nhi;
    for (int s = slo; s < s1; ++s) step((s - nhi) * 32, q0l, qfL, accL, mL, lL);

    // ---- write partials to LDS ----
#pragma unroll
    for (int bnd = 0; bnd < 2; ++bnd) {
        const f32x4 (&acc)[2][4] = bnd ? accL : accH;
        const float (&m2)[2] = bnd ? mL : mH;
        const float (&ls)[2] = bnd ? lL : lH;
        const int slot = bnd * 8 + w;
#pragma unroll
        for (int sub = 0; sub < 2; ++sub) {
#pragma unroll
            for (int fh = 0; fh < 4; ++fh)
                *(f32x4*)&Pacc[slot][16 * sub + lr][16 * fh + 4 * g] = acc[sub][fh];
            if (g == 0) {
                Pml[0][slot][16 * sub + lr] = m2[sub];
                Pml[1][slot][16 * sub + lr] = ls[sub];
            }
        }
    }
    __syncthreads();

    // ---- combine: 512 thr -> 2 bands x 32 q x 8 h-groups ----
    {
        const int tb = t >> 8, t2 = t & 255;
        const int qq = t2 & 31, hb = (t2 >> 5) * 8;
        float mw[8], M = NEG_INF;
#pragma unroll
        for (int wv = 0; wv < 8; ++wv) {
            mw[wv] = Pml[0][tb * 8 + wv][qq];
            M = fmaxf(M, mw[wv]);
        }
        float wgt[8], L = 0.f;
#pragma unroll
        for (int wv = 0; wv < 8; ++wv) {
            wgt[wv] = exp2f(mw[wv] - M);           // exp2(-inf)=0 for idle waves
            L += wgt[wv] * Pml[1][tb * 8 + wv][qq];
        }
        f32x4 o0 = {}, o1 = {};
#pragma unroll
        for (int wv = 0; wv < 8; ++wv) {
            f32x4 a0 = *(const f32x4*)&Pacc[tb * 8 + wv][qq][hb];
            f32x4 a1 = *(const f32x4*)&Pacc[tb * 8 + wv][qq][hb + 4];
            o0 += wgt[wv] * a0;
            o1 += wgt[wv] * a1;
        }
        const float invL = 1.f / L;
        o0 *= invL; o1 *= invL;
        const int q0 = tb ? q0l : q0h;
        float* op = out + (rowbase + q0 + qq) * 64 + hb;
        *(f32x4*)op = o0;
        *(f32x4*)(op + 4) = o1;
    }
}

// ---------------------------------------------------------------------------
extern "C" void kernel_launch(void* const* d_in, const int* in_sizes, int n_in,
                              void* d_out, int out_size, void* d_ws, size_t ws_size,
                              hipStream_t stream) {
    const float* X  = (const float*)d_in[0];
    const float* Wk = (const float*)d_in[1];
    const float* Wq = (const float*)d_in[2];
    const float* Wv = (const float*)d_in[3];

    unsigned short* Wt  = (unsigned short*)d_ws;       // 192*1024 bf16
    unsigned short* Kb  = Wt + 192 * 1024;             // [16384][64] bf16
    unsigned short* Qb  = Kb + 16384 * 64;             // [16384][64] bf16
    unsigned short* Vtg = Qb + 16384 * 64;             // [8][64][2048] bf16 (V^T)
    float* out = (float*)d_out;

    wconv_kernel<<<dim3(192), dim3(256), 0, stream>>>(Wk, Wq, Wv, Wt);
    proj_kernel<<<dim3(1024), dim3(64), 0, stream>>>(X, Wt, Kb, Qb, Vtg);
    attn_kernel<<<dim3(32, 8), dim3(512), 0, stream>>>(Kb, Qb, Vtg, out);
}